// Round 4
// baseline (108.652 us; speedup 1.0000x reference)
//
#include <hip/hip_runtime.h>
#include <math.h>

// Problem constants (reference: B=8, N=4096, M=4096, D=2)
#define NB 8
#define NPTS 4096
#define MPTS 4096
#define BN (NB * NPTS)            // 32768 predicted points total
#define P 4                       // predicted points per lane
#define WV 4                      // waves per block (256 threads)
#define THREADS (WV * 64)
#define TT 128                    // targets per slice
#define NS (MPTS / TT)            // 32 slices
#define PREDS_PER_BLOCK (THREADS * P)   // 1024
#define PGROUPS (BN / PREDS_PER_BLOCK)  // 32

__device__ __forceinline__ float waveReduceSum(float v) {
#pragma unroll
    for (int off = 32; off > 0; off >>= 1)
        v += __shfl_down(v, off, 64);
    return v;
}

// Single fused kernel. Grid = PGROUPS*NS = 1024 blocks x 256 threads.
// Phase 1: block (pg, s) computes min_t over its 128-target slice for its
//   1024 preds (P=4/lane, 3 VALU/pair, LDS uniform-broadcast reads).
// Phase 2: last-arriving block of each pg (monotonic counter mod NS — works
//   for ANY initial counter value, so no init dispatch and poison-safe)
//   min-combines the 32 slices in fixed order, masks, reduces -> partials[pg].
// Phase 3: last group-combiner (counter mod PGROUPS) computes the 3 scalars
//   in fixed batch order -> bitwise deterministic output.
__global__ __launch_bounds__(THREADS) void fused_kernel(
    const float2* __restrict__ pred,    // [B*N]
    const int* __restrict__ pcounts,    // [B]
    const float2* __restrict__ tgt,     // [B][M]
    const int* __restrict__ tcounts,    // [B]
    unsigned int* __restrict__ cnt,     // [PGROUPS] monotonic
    unsigned int* __restrict__ cnt2,    // [1] monotonic
    float* __restrict__ partials,       // [PGROUPS]
    float* __restrict__ mins,           // [NS][B*N]
    float* __restrict__ out)            // [3]: total, coord, points
{
    __shared__ float sx[TT], sy[TT], sc[TT];
    __shared__ float wsum[WV];
    __shared__ unsigned int strig;

    const int bid = blockIdx.x;
    const int s  = bid & (NS - 1);
    const int pg = bid >> 5;
    const int b  = pg >> 2;             // PGROUPS/NB = 4 groups per batch
    const int tid = threadIdx.x;
    const int w = tid >> 6, lane = tid & 63;

    // ---- Phase 1: slice min ----
    const int tcount = tcounts[b];
    const int tstart = s * TT;
    const int tloc = min(tcount - tstart, TT);   // may be <= 0 (dead slice)

    if (tid < TT) {
        float2 t = tgt[(size_t)b * MPTS + tstart + tid];
        sx[tid] = -2.0f * t.x;
        sy[tid] = -2.0f * t.y;
        sc[tid] = fmaf(t.x, t.x, t.y * t.y);
    }
    __syncthreads();

    const size_t pbase = (size_t)pg * PREDS_PER_BLOCK + w * (64 * P) + lane;
    const float2 p0 = pred[pbase];
    const float2 p1 = pred[pbase + 64];
    const float2 p2 = pred[pbase + 128];
    const float2 p3 = pred[pbase + 192];

    float mn0 = INFINITY, mn1 = INFINITY, mn2 = INFINITY, mn3 = INFINITY;
    if (tloc > 0) {
        const float4* x4 = (const float4*)sx;
        const float4* y4 = (const float4*)sy;
        const float4* c4 = (const float4*)sc;
        const int nt4 = tloc >> 2;
#pragma unroll 2
        for (int i = 0; i < nt4; ++i) {
            float4 xv = x4[i], yv = y4[i], cv = c4[i];
            mn0 = fminf(mn0, fmaf(p0.y, yv.x, fmaf(p0.x, xv.x, cv.x)));
            mn1 = fminf(mn1, fmaf(p1.y, yv.x, fmaf(p1.x, xv.x, cv.x)));
            mn2 = fminf(mn2, fmaf(p2.y, yv.x, fmaf(p2.x, xv.x, cv.x)));
            mn3 = fminf(mn3, fmaf(p3.y, yv.x, fmaf(p3.x, xv.x, cv.x)));
            mn0 = fminf(mn0, fmaf(p0.y, yv.y, fmaf(p0.x, xv.y, cv.y)));
            mn1 = fminf(mn1, fmaf(p1.y, yv.y, fmaf(p1.x, xv.y, cv.y)));
            mn2 = fminf(mn2, fmaf(p2.y, yv.y, fmaf(p2.x, xv.y, cv.y)));
            mn3 = fminf(mn3, fmaf(p3.y, yv.y, fmaf(p3.x, xv.y, cv.y)));
            mn0 = fminf(mn0, fmaf(p0.y, yv.z, fmaf(p0.x, xv.z, cv.z)));
            mn1 = fminf(mn1, fmaf(p1.y, yv.z, fmaf(p1.x, xv.z, cv.z)));
            mn2 = fminf(mn2, fmaf(p2.y, yv.z, fmaf(p2.x, xv.z, cv.z)));
            mn3 = fminf(mn3, fmaf(p3.y, yv.z, fmaf(p3.x, xv.z, cv.z)));
            mn0 = fminf(mn0, fmaf(p0.y, yv.w, fmaf(p0.x, xv.w, cv.w)));
            mn1 = fminf(mn1, fmaf(p1.y, yv.w, fmaf(p1.x, xv.w, cv.w)));
            mn2 = fminf(mn2, fmaf(p2.y, yv.w, fmaf(p2.x, xv.w, cv.w)));
            mn3 = fminf(mn3, fmaf(p3.y, yv.w, fmaf(p3.x, xv.w, cv.w)));
        }
        for (int m = nt4 * 4; m < tloc; ++m) {
            float xs = sx[m], ys = sy[m], cs = sc[m];
            mn0 = fminf(mn0, fmaf(p0.y, ys, fmaf(p0.x, xs, cs)));
            mn1 = fminf(mn1, fmaf(p1.y, ys, fmaf(p1.x, xs, cs)));
            mn2 = fminf(mn2, fmaf(p2.y, ys, fmaf(p2.x, xs, cs)));
            mn3 = fminf(mn3, fmaf(p3.y, ys, fmaf(p3.x, xs, cs)));
        }
    }
    {
        float* dst = mins + (size_t)s * BN + pbase;
        dst[0]   = mn0;
        dst[64]  = mn1;
        dst[128] = mn2;
        dst[192] = mn3;
    }

    // ---- Signal: release stores, bump group counter ----
    __threadfence();
    __syncthreads();
    if (tid == 0) {
        unsigned int old = atomicAdd(&cnt[pg], 1u);
        strig = (((old + 1u) & (NS - 1)) == 0u) ? 1u : 0u;
    }
    __syncthreads();

    // ---- Phase 2: last block of this pred-group combines the 32 slices ----
    if (strig) {
        __threadfence();   // acquire: see all slices' stores
        const size_t gbase = (size_t)pg * PREDS_PER_BLOCK;
        const int pcount = pcounts[b];
        float sum = 0.0f;
#pragma unroll
        for (int k = 0; k < P; ++k) {
            const size_t gi = gbase + tid + k * THREADS;
            float v = mins[gi];
#pragma unroll
            for (int ss = 1; ss < NS; ++ss)
                v = fminf(v, mins[(size_t)ss * BN + gi]);
            float2 p = pred[gi];
            v += fmaf(p.x, p.x, p.y * p.y);
            const int nb = (int)(gi & (NPTS - 1));
            sum += (nb < pcount) ? v : 0.0f;
        }
        sum = waveReduceSum(sum);
        if (lane == 0) wsum[w] = sum;
        __syncthreads();
        if (tid == 0) {
            float tot = (wsum[0] + wsum[1]) + (wsum[2] + wsum[3]);
            partials[pg] = tot;
            __threadfence();
            unsigned int old2 = atomicAdd(cnt2, 1u);
            // ---- Phase 3: last group-combiner emits the 3 scalars ----
            if (((old2 + 1u) & (PGROUPS - 1)) == 0u) {
                __threadfence();
                float coord = 0.0f, pts = 0.0f;
                for (int bb = 0; bb < NB; ++bb) {
                    float sb = (partials[4 * bb] + partials[4 * bb + 1]) +
                               (partials[4 * bb + 2] + partials[4 * bb + 3]);
                    coord += sb / ((float)pcounts[bb] * 2.0f);
                    float d = ((float)pcounts[bb] - (float)tcounts[bb]) * (1.0f / NPTS);
                    pts += d * d;
                }
                coord *= (1.0f / NB);
                pts *= (1.0f / NB);
                out[0] = coord + 0.1f * pts;
                out[1] = coord;
                out[2] = pts;
            }
        }
    }
}

extern "C" void kernel_launch(void* const* d_in, const int* in_sizes, int n_in,
                              void* d_out, int out_size, void* d_ws, size_t ws_size,
                              hipStream_t stream) {
    const float2* pred    = (const float2*)d_in[0];
    const int*    pcounts = (const int*)d_in[1];
    const float2* tgt     = (const float2*)d_in[2];
    const int*    tcounts = (const int*)d_in[3];
    float* out = (float*)d_out;

    unsigned int* cnt  = (unsigned int*)d_ws;          // [32] monotonic
    unsigned int* cnt2 = cnt + PGROUPS;                // [1]  monotonic
    float* partials = (float*)(cnt + 2 * PGROUPS);     // [32]
    float* mins     = (float*)((char*)d_ws + 1024);    // [NS][BN], 4 MB

    fused_kernel<<<PGROUPS * NS, THREADS, 0, stream>>>(
        pred, pcounts, tgt, tcounts, cnt, cnt2, partials, mins, out);
}

// Round 5
// 19.265 us; speedup vs baseline: 5.6399x; 5.6399x over previous
//
#include <hip/hip_runtime.h>
#include <math.h>

// Problem constants (reference: B=8, N=4096, M=4096, D=2)
#define NB 8
#define NPTS 4096
#define MPTS 4096
#define BN (NB * NPTS)            // 32768 predicted points
#define K1_THREADS 1024
#define K1_WAVES 16
#define SLICE (MPTS / K1_WAVES)   // 256 targets per wave slice
#define P 2                       // predicted points per lane
#define PPB (64 * P)              // 128 preds per block
#define NBLK (BN / PPB)           // 256 blocks (1 per CU)
#define BPB (NPTS / PPB)          // 32 blocks per batch

typedef float v2f __attribute__((ext_vector_type(2)));

static __device__ __forceinline__ v2f pk_fma(v2f a, v2f b, v2f c) {
    v2f d;
    asm("v_pk_fma_f32 %0, %1, %2, %3" : "=v"(d) : "v"(a), "v"(b), "v"(c));
    return d;
}
static __device__ __forceinline__ v2f pk_mul(v2f a, v2f b) {
    v2f d;
    asm("v_pk_mul_f32 %0, %1, %2" : "=v"(d) : "v"(a), "v"(b));
    return d;
}
static __device__ __forceinline__ float min3f(float a, float b, float c) {
    float d;
    asm("v_min3_f32 %0, %1, %2, %3" : "=v"(d) : "v"(a), "v"(b), "v"(c));
    return d;
}

__device__ __forceinline__ float waveReduceSum(float v) {
#pragma unroll
    for (int off = 32; off > 0; off >>= 1)
        v += __shfl_down(v, off, 64);
    return v;
}

// One block = 128 preds of one batch x ALL 4096 targets (staged raw in LDS).
// 16 waves each scan a 256-target slice; cross-wave min via LDS+syncthreads
// (no global fences). Inner math: min ||p-t||^2 = p.p + min(t.t - 2p.t),
// packed fp32: per 2 targets, shared c=t.t (pk_mul+pk_fma) + per pred
// 2 pk_fma + 1 v_min3 -> 2.0 VALU instr/pair, 2 broadcast b128 per 4 targets.
__global__ __launch_bounds__(K1_THREADS) void nn_kernel(
    const float2* __restrict__ pred,    // [B*N]
    const int* __restrict__ pcounts,    // [B]
    const float2* __restrict__ tgt,     // [B][M]
    const int* __restrict__ tcounts,    // [B]
    float* __restrict__ partials)       // [NBLK]
{
    __shared__ float sx[MPTS];          // 16 KB
    __shared__ float sy[MPTS];          // 16 KB
    __shared__ float mnw[K1_WAVES][PPB];// 8 KB
    __shared__ float wsum[2];

    const int bid = blockIdx.x;
    const int b = bid >> 5;             // / BPB
    const int tid = threadIdx.x;
    const int w = tid >> 6, lane = tid & 63;

    // Stage raw targets (deinterleave x/y), 2 float4 per thread.
    {
        const float4* t4 = (const float4*)(tgt + (size_t)b * MPTS);
        float4 f0 = t4[tid];
        float4 f1 = t4[tid + K1_THREADS];
        *(v2f*)&sx[2 * tid] = (v2f){f0.x, f0.z};
        *(v2f*)&sy[2 * tid] = (v2f){f0.y, f0.w};
        *(v2f*)&sx[2 * (tid + K1_THREADS)] = (v2f){f1.x, f1.z};
        *(v2f*)&sy[2 * (tid + K1_THREADS)] = (v2f){f1.y, f1.w};
    }

    const size_t pbase = (size_t)bid * PPB + lane;
    const float2 p0 = pred[pbase];
    const float2 p1 = pred[pbase + 64];
    const v2f n2x0 = {-2.0f * p0.x, -2.0f * p0.x};
    const v2f n2y0 = {-2.0f * p0.y, -2.0f * p0.y};
    const v2f n2x1 = {-2.0f * p1.x, -2.0f * p1.x};
    const v2f n2y1 = {-2.0f * p1.y, -2.0f * p1.y};

    const int tcount = tcounts[b];
    const int pcount = pcounts[b];
    const int tstart = w * SLICE;
    int tloc = min(tcount - tstart, SLICE);
    if (tloc < 0) tloc = 0;

    __syncthreads();

    float a00 = INFINITY, a01 = INFINITY, a10 = INFINITY, a11 = INFINITY;
    const float4* x4 = (const float4*)&sx[tstart];
    const float4* y4 = (const float4*)&sy[tstart];
    const int nt4 = tloc >> 2;
#pragma unroll 2
    for (int i = 0; i < nt4; ++i) {
        float4 xv = x4[i], yv = y4[i];
        v2f x01 = {xv.x, xv.y}, x23 = {xv.z, xv.w};
        v2f y01 = {yv.x, yv.y}, y23 = {yv.z, yv.w};
        v2f c01 = pk_fma(x01, x01, pk_mul(y01, y01));
        v2f c23 = pk_fma(x23, x23, pk_mul(y23, y23));
        v2f t;
        t = pk_fma(n2y0, y01, pk_fma(n2x0, x01, c01)); a00 = min3f(a00, t.x, t.y);
        t = pk_fma(n2y0, y23, pk_fma(n2x0, x23, c23)); a01 = min3f(a01, t.x, t.y);
        t = pk_fma(n2y1, y01, pk_fma(n2x1, x01, c01)); a10 = min3f(a10, t.x, t.y);
        t = pk_fma(n2y1, y23, pk_fma(n2x1, x23, c23)); a11 = min3f(a11, t.x, t.y);
    }
    for (int m = nt4 * 4; m < tloc; ++m) {
        float tx = sx[tstart + m], ty = sy[tstart + m];
        float cc = fmaf(tx, tx, ty * ty);
        a00 = fminf(a00, fmaf(n2y0.x, ty, fmaf(n2x0.x, tx, cc)));
        a10 = fminf(a10, fmaf(n2y1.x, ty, fmaf(n2x1.x, tx, cc)));
    }
    mnw[w][lane] = fminf(a00, a01);
    mnw[w][lane + 64] = fminf(a10, a11);
    __syncthreads();

    // Cross-wave min + p.p + mask + fixed-order block sum (waves 0,1 only).
    if (tid < PPB) {
        float v = mnw[0][tid];
#pragma unroll
        for (int j = 1; j < K1_WAVES; ++j) v = fminf(v, mnw[j][tid]);
        const size_t pg = (size_t)bid * PPB + tid;
        float2 pp = pred[pg];
        v += fmaf(pp.x, pp.x, pp.y * pp.y);
        const int n = (int)(pg & (NPTS - 1));
        v = (n < pcount) ? v : 0.0f;
        v = waveReduceSum(v);
        if ((tid & 63) == 0) wsum[tid >> 6] = v;
    }
    __syncthreads();
    if (tid == 0) partials[bid] = wsum[0] + wsum[1];
}

// Final: 1 wave. Lanes 0-7 serially sum their batch's 32 partials (fixed
// order -> deterministic), then a fixed-order shfl combine across batches.
__global__ __launch_bounds__(64) void final_kernel(
    const float* __restrict__ partials, // [NBLK]
    const int* __restrict__ pcounts,
    const int* __restrict__ tcounts,
    float* __restrict__ out)            // [3]: total, coord, points
{
    const int lane = threadIdx.x;
    float coord_l = 0.0f, pts_l = 0.0f;
    if (lane < NB) {
        float s = 0.0f;
        for (int k = 0; k < BPB; ++k) s += partials[lane * BPB + k];
        float pc = (float)pcounts[lane];
        coord_l = s / (pc * 2.0f);
        float d = (pc - (float)tcounts[lane]) * (1.0f / NPTS);
        pts_l = d * d;
    }
    float coord = 0.0f, pts = 0.0f;
#pragma unroll
    for (int b2 = 0; b2 < NB; ++b2) {
        coord += __shfl(coord_l, b2, 64);
        pts   += __shfl(pts_l, b2, 64);
    }
    if (lane == 0) {
        coord *= (1.0f / NB);
        pts *= (1.0f / NB);
        out[0] = coord + 0.1f * pts;
        out[1] = coord;
        out[2] = pts;
    }
}

extern "C" void kernel_launch(void* const* d_in, const int* in_sizes, int n_in,
                              void* d_out, int out_size, void* d_ws, size_t ws_size,
                              hipStream_t stream) {
    const float2* pred    = (const float2*)d_in[0];
    const int*    pcounts = (const int*)d_in[1];
    const float2* tgt     = (const float2*)d_in[2];
    const int*    tcounts = (const int*)d_in[3];
    float* out = (float*)d_out;

    float* partials = (float*)d_ws;     // NBLK floats

    nn_kernel<<<NBLK, K1_THREADS, 0, stream>>>(pred, pcounts, tgt, tcounts, partials);
    final_kernel<<<1, 64, 0, stream>>>(partials, pcounts, tcounts, out);
}